// Round 13
// baseline (47.904 us; speedup 1.0000x reference)
//
#include <hip/hip_runtime.h>
#include <hip/hip_bf16.h>

#define N_ROWS 8192
#define DIM 128
#define MARGIN_F 0.3f

typedef __attribute__((ext_vector_type(8))) short short8;
typedef __attribute__((ext_vector_type(4))) float f32x4;
typedef __attribute__((ext_vector_type(4))) int int4v;

// ---------------- Kernel A: fp32 -> bf16 (fragment-major), norms, init ----
// Fragment-major layout: 16B unit u = c16*256 + kk*64 + l4*16 + l15 holds
// bf16 elems [kk*32 + l4*8 .. +8) of row (c16*16 + l15). An MFMA A/B-fragment
// load for 16-row panel c16 is xf[c16*256 + kk*64 + lane]: 64 lanes contiguous.
// xbA holds -2*x (exact bf16 pow2 scale) so seeding acc with sqc makes the
// MFMA emit v = sqc - 2*s directly (epilogue: no add).
__global__ __launch_bounds__(256) void prep_kernel(
    const float* __restrict__ x, const int* __restrict__ tgt,
    unsigned short* __restrict__ xbA, unsigned short* __restrict__ xbB,
    float2* __restrict__ meta, int* __restrict__ apb, int* __restrict__ anb) {
  const int w = threadIdx.x >> 6, l = threadIdx.x & 63;
  const int row = blockIdx.x * 4 + w;
  float2 v = reinterpret_cast<const float2*>(x + (size_t)row * DIM)[l];
  __hip_bfloat16 b0 = __float2bfloat16(v.x);
  __hip_bfloat16 b1 = __float2bfloat16(v.y);
  __hip_bfloat16 a0 = __float2bfloat16(-2.f * v.x);
  __hip_bfloat16 a1 = __float2bfloat16(-2.f * v.y);
  ushort2 stB, stA;
  stB.x = *reinterpret_cast<unsigned short*>(&b0);
  stB.y = *reinterpret_cast<unsigned short*>(&b1);
  stA.x = *reinterpret_cast<unsigned short*>(&a0);
  stA.y = *reinterpret_cast<unsigned short*>(&a1);
  const int c16 = row >> 4, l15r = row & 15;
  const int unit = c16 * 256 + (l >> 4) * 64 + ((l >> 2) & 3) * 16 + l15r;
  reinterpret_cast<ushort2*>(xbB)[unit * 4 + (l & 3)] = stB;
  reinterpret_cast<ushort2*>(xbA)[unit * 4 + (l & 3)] = stA;

  float s = v.x * v.x + v.y * v.y;
  #pragma unroll
  for (int off = 32; off >= 1; off >>= 1) s += __shfl_xor(s, off);
  if (l == 0) {
    float2 m;
    m.x = s;
    m.y = __int_as_float(tgt[row]);   // raw bit carry; only ever bit-compared
    meta[row] = m;
    apb[row] = 0x00000000;            // 0.0f (max identity; diagonal is positive)
    anb[row] = 0x7f800000;            // +inf (min identity)
  }
}

// ---------------- Kernel B: fused Gram + mining, 2-tile-lead pipeline ------
// NO LDS, NO barriers. grid (64,16) x 4 waves = 4096 waves, 2 generations.
// Wave = 32 rows x 32 cols per tile, 16 tiles (512-col chunk). 4-slot B+meta
// rotation: PREF(t+2) issues at the TOP of tile-t's phase, so every B frag
// and the acc-seed meta are ~2 tiles (~1100+ cyc) old when consumed — fixes
// r8's two critical-path stalls (1-tile B lead; 0-cycle-old acc seed).
__global__ __launch_bounds__(256, 2) void gram_mine_kernel(
    const unsigned short* __restrict__ xbA, const unsigned short* __restrict__ xbB,
    const float2* __restrict__ meta, int* __restrict__ apb, int* __restrict__ anb) {
  const int t = threadIdx.x;
  const int w = t >> 6, l = t & 63;
  const int l15 = l & 15, l4 = l >> 4;
  const int rb = blockIdx.x * 128 + w * 32;      // wave's global row base
  const int chunk = blockIdx.y * 512;            // 512 cols per chunk (16 tiles)
  const int chunkb = chunk >> 4;

  const short8* xfA = reinterpret_cast<const short8*>(xbA);
  const short8* xfB = reinterpret_cast<const short8*>(xbB);

  // A fragments (-2x): panels (rb>>4), (rb>>4)+1 (rows rb..rb+31)
  short8 a0[4], a1[4];
  #pragma unroll
  for (int kk = 0; kk < 4; ++kk) {
    a0[kk] = xfA[(rb >> 4) * 256 + kk * 64 + l];
    a1[kk] = xfA[((rb >> 4) + 1) * 256 + kk * 64 + l];
  }

  // per-lane row classes (C/D layout rows: rb + rf*16 + l4*4 + rg)
  int t_r[8];
  #pragma unroll
  for (int rf = 0; rf < 2; ++rf)
    #pragma unroll
    for (int rg = 0; rg < 4; ++rg)
      t_r[rf * 4 + rg] = __float_as_int(meta[rb + rf * 16 + l4 * 4 + rg].y);

  // mining state on v = sqc - 2*s (row term +sq_r deferred to the end)
  float ap2[8], an2[8];
  #pragma unroll
  for (int i = 0; i < 8; ++i) { ap2[i] = -__builtin_inff(); an2[i] = __builtin_inff(); }

  // 4-slot rotation: tile i lives in slot i%4 (B frags + meta), all static.
  short8 b0[8], b1[8], b2[8], b3[8];
  float2 m0[2], m1[2], m2[2], m3[2];
  f32x4 accA[2][2], accB[2][2];       // even / odd tile accumulators

#define PREF(IDX, BB, MC) do {                                                \
    const int cb16_ = chunkb + (IDX) * 2;                                     \
    _Pragma("unroll")                                                         \
    for (int kk_ = 0; kk_ < 4; ++kk_) {                                       \
      BB[kk_ * 2 + 0] = xfB[(cb16_ + 0) * 256 + kk_ * 64 + l];                \
      BB[kk_ * 2 + 1] = xfB[(cb16_ + 1) * 256 + kk_ * 64 + l];                \
    }                                                                         \
    MC[0] = meta[chunk + (IDX) * 32 + l15];                                   \
    MC[1] = meta[chunk + (IDX) * 32 + 16 + l15]; } while (0)

#define MFMA_T(BB, MC, ACC) do {                                              \
    _Pragma("unroll")                                                         \
    for (int cf_ = 0; cf_ < 2; ++cf_) {                                       \
      float s_ = MC[cf_].x;                                                   \
      f32x4 ci_ = {s_, s_, s_, s_};                                           \
      ACC[0][cf_] = ci_; ACC[1][cf_] = ci_;                                   \
    }                                                                         \
    __builtin_amdgcn_s_setprio(1);                                            \
    _Pragma("unroll")                                                         \
    for (int kk_ = 0; kk_ < 4; ++kk_) {                                       \
      _Pragma("unroll")                                                       \
      for (int cf_ = 0; cf_ < 2; ++cf_) {                                     \
        ACC[0][cf_] = __builtin_amdgcn_mfma_f32_16x16x32_bf16(                \
            a0[kk_], BB[kk_ * 2 + cf_], ACC[0][cf_], 0, 0, 0);                \
        ACC[1][cf_] = __builtin_amdgcn_mfma_f32_16x16x32_bf16(                \
            a1[kk_], BB[kk_ * 2 + cf_], ACC[1][cf_], 0, 0, 0);                \
      } }                                                                     \
    __builtin_amdgcn_s_setprio(0); } while (0)

#define EPI_T(ACC, MC) do {                                                   \
    _Pragma("unroll")                                                         \
    for (int cf_ = 0; cf_ < 2; ++cf_) {                                       \
      const int tc_ = __float_as_int(MC[cf_].y);                              \
      _Pragma("unroll")                                                       \
      for (int rf_ = 0; rf_ < 2; ++rf_) {                                     \
        _Pragma("unroll")                                                     \
        for (int rg_ = 0; rg_ < 4; ++rg_) {                                   \
          const int ix_ = rf_ * 4 + rg_;                                      \
          float v_ = ACC[rf_][cf_][rg_];                                      \
          bool p_ = (t_r[ix_] == tc_);                                        \
          ap2[ix_] = p_ ? fmaxf(ap2[ix_], v_) : ap2[ix_];                     \
          an2[ix_] = p_ ? an2[ix_] : fminf(an2[ix_], v_);                     \
        } } } } while (0)

  // prologue: tiles 0..3 in flight, 2-tile lead established
  PREF(0, b0, m0);
  PREF(1, b1, m1);
  PREF(2, b2, m2); MFMA_T(b0, m0, accA);
  PREF(3, b3, m3); MFMA_T(b1, m1, accB); EPI_T(accA, m0);   // E(0)

  // steady state: per tile {PREF(t+2) ; MFMA(t) ; EPI(t-1)} — P leads M by 2
  #pragma unroll 1
  for (int q = 0; q < 3; ++q) {
    const int tb = 4 * q + 2;
    PREF(tb + 2, b0, m0); MFMA_T(b2, m2, accA); EPI_T(accB, m1);  // M(t)  E(t-1)
    PREF(tb + 3, b1, m1); MFMA_T(b3, m3, accB); EPI_T(accA, m2);  // M(t+1) E(t)
    PREF(tb + 4, b2, m2); MFMA_T(b0, m0, accA); EPI_T(accB, m3);  // M(t+2) E(t+1)
    PREF(tb + 5, b3, m3); MFMA_T(b1, m1, accB); EPI_T(accA, m0);  // M(t+3) E(t+2)
  }
  // tail: tiles 14, 15 (already prefetched in q=2)
  MFMA_T(b2, m2, accA); EPI_T(accB, m1);   // M(14) E(13)
  MFMA_T(b3, m3, accB); EPI_T(accA, m2);   // M(15) E(14)
  EPI_T(accB, m3);                         // E(15)

#undef PREF
#undef MFMA_T
#undef EPI_T

  // reduce across the 16 lanes (same l4 group = same rows, different cols)
  #pragma unroll
  for (int i = 0; i < 8; ++i) {
    #pragma unroll
    for (int off = 1; off < 16; off <<= 1) {
      ap2[i] = fmaxf(ap2[i], __shfl_xor(ap2[i], off));
      an2[i] = fminf(an2[i], __shfl_xor(an2[i], off));
    }
  }
  if (l15 == 0) {
    #pragma unroll
    for (int rf = 0; rf < 2; ++rf)
      #pragma unroll
      for (int rg = 0; rg < 4; ++rg) {
        int row = rb + rf * 16 + l4 * 4 + rg;
        float sqr = meta[row].x;
        // d^2 = v + sq_r; clamp >=1e-12 commutes with max/min; non-negative
        // floats are int-monotone -> int atomics give exact fp max/min.
        float a2 = fmaxf(ap2[rf * 4 + rg] + sqr, 1e-12f);
        float n2 = fmaxf(an2[rf * 4 + rg] + sqr, 1e-12f);
        atomicMax(apb + row, __float_as_int(a2));
        atomicMin(anb + row, __float_as_int(n2));
      }
  }
}

// ---------------- Kernel C: loss = mean(relu(sqrt(ap2)-sqrt(an2)+margin)) --
__global__ __launch_bounds__(1024) void loss_kernel(
    const int4v* __restrict__ apb, const int4v* __restrict__ anb,
    float* __restrict__ out) {
  __shared__ float red[16];
  float s = 0.f;
  for (int i = threadIdx.x; i < N_ROWS / 4; i += 1024) {
    int4v a4 = apb[i], n4 = anb[i];
    #pragma unroll
    for (int j = 0; j < 4; ++j) {
      float ap = sqrtf(__int_as_float(a4[j]));
      float an = sqrtf(__int_as_float(n4[j]));   // +inf sentinel -> relu(-inf)=0
      float li = ap - an + MARGIN_F;
      s += li > 0.f ? li : 0.f;
    }
  }
  #pragma unroll
  for (int off = 32; off >= 1; off >>= 1) s += __shfl_xor(s, off);
  const int w = threadIdx.x >> 6, l = threadIdx.x & 63;
  if (l == 0) red[w] = s;
  __syncthreads();
  if (threadIdx.x < 16) {
    float v = red[threadIdx.x];
    #pragma unroll
    for (int off = 8; off >= 1; off >>= 1) v += __shfl_xor(v, off);
    if (threadIdx.x == 0) out[0] = v / (float)N_ROWS;
  }
}

extern "C" void kernel_launch(void* const* d_in, const int* in_sizes, int n_in,
                              void* d_out, int out_size, void* d_ws, size_t ws_size,
                              hipStream_t stream) {
  const float* x = (const float*)d_in[0];
  const int* tgt = (const int*)d_in[1];
  float* out = (float*)d_out;

  char* ws = (char*)d_ws;
  unsigned short* xbA = (unsigned short*)ws;                // 2 MB frag-major -2x
  unsigned short* xbB = (unsigned short*)(ws + 2097152);    // 2 MB frag-major  x
  float2* meta = (float2*)(ws + 4194304);                   // 64 KB (sq, tgt)
  int* apb = (int*)(ws + 4194304 + 65536);                  // 32 KB ap^2 bits
  int* anb = (int*)(ws + 4194304 + 65536 + 32768);          // 32 KB an^2 bits

  prep_kernel<<<2048, 256, 0, stream>>>(x, tgt, xbA, xbB, meta, apb, anb);
  gram_mine_kernel<<<dim3(64, 16), 256, 0, stream>>>(xbA, xbB, meta, apb, anb);
  loss_kernel<<<1, 1024, 0, stream>>>((const int4v*)apb, (const int4v*)anb, out);
}

// Round 14
// 45.292 us; speedup vs baseline: 1.0577x; 1.0577x over previous
//
#include <hip/hip_runtime.h>
#include <hip/hip_bf16.h>

#define N_ROWS 8192
#define DIM 128
#define MARGIN_F 0.3f

typedef __attribute__((ext_vector_type(8))) short short8;
typedef __attribute__((ext_vector_type(4))) float f32x4;
typedef __attribute__((ext_vector_type(4))) int int4v;

// ---------------- Kernel A: fp32 -> bf16 (fragment-major), norms, init ----
// Fragment-major layout: 16B unit u = c16*256 + kk*64 + l4*16 + l15 holds
// bf16 elems [kk*32 + l4*8 .. +8) of row (c16*16 + l15). An MFMA A/B-fragment
// load for 16-row panel c16 is xf[c16*256 + kk*64 + lane]: 64 lanes contiguous.
// xbA holds -2*x (exact bf16 pow2 scale) so seeding acc with sqc makes the
// MFMA emit v = sqc - 2*s directly (epilogue: no add).
__global__ __launch_bounds__(256) void prep_kernel(
    const float* __restrict__ x, const int* __restrict__ tgt,
    unsigned short* __restrict__ xbA, unsigned short* __restrict__ xbB,
    float2* __restrict__ meta, int* __restrict__ apb, int* __restrict__ anb) {
  const int w = threadIdx.x >> 6, l = threadIdx.x & 63;
  const int row = blockIdx.x * 4 + w;
  float2 v = reinterpret_cast<const float2*>(x + (size_t)row * DIM)[l];
  __hip_bfloat16 b0 = __float2bfloat16(v.x);
  __hip_bfloat16 b1 = __float2bfloat16(v.y);
  __hip_bfloat16 a0 = __float2bfloat16(-2.f * v.x);
  __hip_bfloat16 a1 = __float2bfloat16(-2.f * v.y);
  ushort2 stB, stA;
  stB.x = *reinterpret_cast<unsigned short*>(&b0);
  stB.y = *reinterpret_cast<unsigned short*>(&b1);
  stA.x = *reinterpret_cast<unsigned short*>(&a0);
  stA.y = *reinterpret_cast<unsigned short*>(&a1);
  const int c16 = row >> 4, l15r = row & 15;
  const int unit = c16 * 256 + (l >> 4) * 64 + ((l >> 2) & 3) * 16 + l15r;
  reinterpret_cast<ushort2*>(xbB)[unit * 4 + (l & 3)] = stB;
  reinterpret_cast<ushort2*>(xbA)[unit * 4 + (l & 3)] = stA;

  float s = v.x * v.x + v.y * v.y;
  #pragma unroll
  for (int off = 32; off >= 1; off >>= 1) s += __shfl_xor(s, off);
  if (l == 0) {
    float2 m;
    m.x = s;
    m.y = __int_as_float(tgt[row]);   // raw bit carry; only ever bit-compared
    meta[row] = m;
    apb[row] = 0x00000000;            // 0.0f (max identity; diagonal is positive)
    anb[row] = 0x7f800000;            // +inf (min identity)
  }
}

// ---------------- Kernel B: fused Gram + mining, rf=4 + phase-top lead -----
// NO LDS, NO barriers. grid (32,16) = 512 blocks = 2/CU, 2048 waves = 2/SIMD.
// Wave = 64 rows x 32 cols per tile, 16 tiles (512-col chunk). The two levers
// that were only ever tried separately, combined:
//  * rf=4 (64 rows/wave): B L1-traffic halves to 268 MB -> L1-BW floor 6.8us,
//    now BELOW the 8.3us MFMA floor;
//  * prefetch at PHASE TOP: PREF(t+1) issues before tile-t's 32-MFMA cluster
//    (~1240 cyc wall at 2 waves/SIMD) -> 1-tile ping-pong lead covers the
//    ~900 cyc worst-case cross-XCD L2 latency, no 4-slot register cost.
// Single acc set; EPI runs right after MFMA (sibling wave overlaps it).
__global__ __launch_bounds__(256, 2) void gram_mine_kernel(
    const unsigned short* __restrict__ xbA, const unsigned short* __restrict__ xbB,
    const float2* __restrict__ meta, int* __restrict__ apb, int* __restrict__ anb) {
  const int t = threadIdx.x;
  const int w = t >> 6, l = t & 63;
  const int l15 = l & 15, l4 = l >> 4;
  const int rb = blockIdx.x * 256 + w * 64;      // wave's global row base
  const int chunk = blockIdx.y * 512;            // 512 cols per chunk (16 tiles)
  const int chunkb = chunk >> 4;

  const short8* xfA = reinterpret_cast<const short8*>(xbA);
  const short8* xfB = reinterpret_cast<const short8*>(xbB);

  // A fragments (-2x): panels (rb>>4)+rf, rf=0..3 (rows rb..rb+63)
  short8 a[4][4];
  #pragma unroll
  for (int rf = 0; rf < 4; ++rf)
    #pragma unroll
    for (int kk = 0; kk < 4; ++kk)
      a[rf][kk] = xfA[((rb >> 4) + rf) * 256 + kk * 64 + l];

  // per-lane row classes (C/D layout rows: rb + rf*16 + l4*4 + rg)
  int t_r[16];
  #pragma unroll
  for (int rf = 0; rf < 4; ++rf)
    #pragma unroll
    for (int rg = 0; rg < 4; ++rg)
      t_r[rf * 4 + rg] = __float_as_int(meta[rb + rf * 16 + l4 * 4 + rg].y);

  // mining state on v = sqc - 2*s (row term +sq_r deferred to the end)
  float ap2[16], an2[16];
  #pragma unroll
  for (int i = 0; i < 16; ++i) { ap2[i] = -__builtin_inff(); an2[i] = __builtin_inff(); }

  // ping-pong B (8 frags = kk x cf) + meta per slot; all indexing static
  short8 b0[8], b1[8];
  float2 m0[2], m1[2];

#define PREF(IDX, BB, MC) do {                                                \
    const int cb16_ = chunkb + (IDX) * 2;                                     \
    _Pragma("unroll")                                                         \
    for (int kk_ = 0; kk_ < 4; ++kk_) {                                       \
      BB[kk_ * 2 + 0] = xfB[(cb16_ + 0) * 256 + kk_ * 64 + l];                \
      BB[kk_ * 2 + 1] = xfB[(cb16_ + 1) * 256 + kk_ * 64 + l];                \
    }                                                                         \
    MC[0] = meta[chunk + (IDX) * 32 + l15];                                   \
    MC[1] = meta[chunk + (IDX) * 32 + 16 + l15]; } while (0)

#define TILE(BB, MC) do {                                                     \
    f32x4 acc_[4][2];                                                         \
    _Pragma("unroll")                                                         \
    for (int cf_ = 0; cf_ < 2; ++cf_) {                                       \
      float s_ = MC[cf_].x;                                                   \
      f32x4 ci_ = {s_, s_, s_, s_};                                           \
      _Pragma("unroll")                                                       \
      for (int rf_ = 0; rf_ < 4; ++rf_) acc_[rf_][cf_] = ci_;                 \
    }                                                                         \
    __builtin_amdgcn_s_setprio(1);                                            \
    _Pragma("unroll")                                                         \
    for (int kk_ = 0; kk_ < 4; ++kk_) {                                       \
      _Pragma("unroll")                                                       \
      for (int cf_ = 0; cf_ < 2; ++cf_) {                                     \
        _Pragma("unroll")                                                     \
        for (int rf_ = 0; rf_ < 4; ++rf_)                                     \
          acc_[rf_][cf_] = __builtin_amdgcn_mfma_f32_16x16x32_bf16(           \
              a[rf_][kk_], BB[kk_ * 2 + cf_], acc_[rf_][cf_], 0, 0, 0);       \
      } }                                                                     \
    __builtin_amdgcn_s_setprio(0);                                            \
    _Pragma("unroll")                                                         \
    for (int cf_ = 0; cf_ < 2; ++cf_) {                                       \
      const int tc_ = __float_as_int(MC[cf_].y);                              \
      _Pragma("unroll")                                                       \
      for (int rf_ = 0; rf_ < 4; ++rf_) {                                     \
        _Pragma("unroll")                                                     \
        for (int rg_ = 0; rg_ < 4; ++rg_) {                                   \
          const int ix_ = rf_ * 4 + rg_;                                      \
          float v_ = acc_[rf_][cf_][rg_];                                     \
          bool p_ = (t_r[ix_] == tc_);                                        \
          ap2[ix_] = p_ ? fmaxf(ap2[ix_], v_) : ap2[ix_];                     \
          an2[ix_] = p_ ? an2[ix_] : fminf(an2[ix_], v_);                     \
        } } } } while (0)

  // prologue + steady state: PREF(t+1) at phase top, then MFMA+EPI of tile t
  PREF(0, b0, m0);
  #pragma unroll 1
  for (int q = 0; q < 7; ++q) {
    PREF(2 * q + 1, b1, m1); TILE(b0, m0);
    PREF(2 * q + 2, b0, m0); TILE(b1, m1);
  }
  PREF(15, b1, m1); TILE(b0, m0);   // tile 14
  TILE(b1, m1);                     // tile 15

#undef PREF
#undef TILE

  // reduce across the 16 lanes (same l4 group = same rows, different cols)
  #pragma unroll
  for (int i = 0; i < 16; ++i) {
    #pragma unroll
    for (int off = 1; off < 16; off <<= 1) {
      ap2[i] = fmaxf(ap2[i], __shfl_xor(ap2[i], off));
      an2[i] = fminf(an2[i], __shfl_xor(an2[i], off));
    }
  }
  if (l15 == 0) {
    #pragma unroll
    for (int rf = 0; rf < 4; ++rf)
      #pragma unroll
      for (int rg = 0; rg < 4; ++rg) {
        int row = rb + rf * 16 + l4 * 4 + rg;
        float sqr = meta[row].x;
        // d^2 = v + sq_r; clamp >=1e-12 commutes with max/min; non-negative
        // floats are int-monotone -> int atomics give exact fp max/min.
        float a2 = fmaxf(ap2[rf * 4 + rg] + sqr, 1e-12f);
        float n2 = fmaxf(an2[rf * 4 + rg] + sqr, 1e-12f);
        atomicMax(apb + row, __float_as_int(a2));
        atomicMin(anb + row, __float_as_int(n2));
      }
  }
}

// ---------------- Kernel C: loss = mean(relu(sqrt(ap2)-sqrt(an2)+margin)) --
__global__ __launch_bounds__(1024) void loss_kernel(
    const int4v* __restrict__ apb, const int4v* __restrict__ anb,
    float* __restrict__ out) {
  __shared__ float red[16];
  float s = 0.f;
  for (int i = threadIdx.x; i < N_ROWS / 4; i += 1024) {
    int4v a4 = apb[i], n4 = anb[i];
    #pragma unroll
    for (int j = 0; j < 4; ++j) {
      float ap = sqrtf(__int_as_float(a4[j]));
      float an = sqrtf(__int_as_float(n4[j]));   // +inf sentinel -> relu(-inf)=0
      float li = ap - an + MARGIN_F;
      s += li > 0.f ? li : 0.f;
    }
  }
  #pragma unroll
  for (int off = 32; off >= 1; off >>= 1) s += __shfl_xor(s, off);
  const int w = threadIdx.x >> 6, l = threadIdx.x & 63;
  if (l == 0) red[w] = s;
  __syncthreads();
  if (threadIdx.x < 16) {
    float v = red[threadIdx.x];
    #pragma unroll
    for (int off = 8; off >= 1; off >>= 1) v += __shfl_xor(v, off);
    if (threadIdx.x == 0) out[0] = v / (float)N_ROWS;
  }
}

extern "C" void kernel_launch(void* const* d_in, const int* in_sizes, int n_in,
                              void* d_out, int out_size, void* d_ws, size_t ws_size,
                              hipStream_t stream) {
  const float* x = (const float*)d_in[0];
  const int* tgt = (const int*)d_in[1];
  float* out = (float*)d_out;

  char* ws = (char*)d_ws;
  unsigned short* xbA = (unsigned short*)ws;                // 2 MB frag-major -2x
  unsigned short* xbB = (unsigned short*)(ws + 2097152);    // 2 MB frag-major  x
  float2* meta = (float2*)(ws + 4194304);                   // 64 KB (sq, tgt)
  int* apb = (int*)(ws + 4194304 + 65536);                  // 32 KB ap^2 bits
  int* anb = (int*)(ws + 4194304 + 65536 + 32768);          // 32 KB an^2 bits

  prep_kernel<<<2048, 256, 0, stream>>>(x, tgt, xbA, xbB, meta, apb, anb);
  gram_mine_kernel<<<dim3(32, 16), 256, 0, stream>>>(xbA, xbB, meta, apb, anb);
  loss_kernel<<<1, 1024, 0, stream>>>((const int4v*)apb, (const int4v*)anb, out);
}